// Round 4
// baseline (790.398 us; speedup 1.0000x reference)
//
#include <hip/hip_runtime.h>
#include <hip/hip_bf16.h>

#define IN_DIM 128
#define OUT_DIM 256
#define KDIM 256            // 2*IN_DIM
#define EPS 1e-12f
#define CB_NODES 128        // nodes per coarse bucket
#define NB_MAX 1024         // max coarse buckets (N<=131072)
#define PART_CHUNK 8192

typedef __attribute__((ext_vector_type(8))) short short8;   // 8 bf16
typedef __attribute__((ext_vector_type(4))) float f32x4;

static __device__ __forceinline__ unsigned short f2bf(float f) {
  __hip_bfloat16 h = __float2bfloat16(f);   // RNE
  return *reinterpret_cast<unsigned short*>(&h);
}
static __device__ __forceinline__ unsigned pack2bf(float a, float b) {
  return (unsigned)f2bf(a) | ((unsigned)f2bf(b) << 16);
}

// ---------------------------------------------------------------------------
// Convert x (f32 [N][128]) into cols 0..127 of hb (bf16 [Mpad][256]).
// ---------------------------------------------------------------------------
__global__ __launch_bounds__(256) void cvt_x(
    const float* __restrict__ x, unsigned short* __restrict__ hb, int N) {
  const int total = N * 32;                 // N*128/4
  const int stride = gridDim.x * blockDim.x;
  for (int idx = blockIdx.x * blockDim.x + threadIdx.x; idx < total; idx += stride) {
    const int row = idx >> 5;
    const int c4 = (idx & 31) * 4;
    const float4 v = *reinterpret_cast<const float4*>(x + (size_t)row * IN_DIM + c4);
    ushort4 o;
    o.x = f2bf(v.x); o.y = f2bf(v.y); o.z = f2bf(v.z); o.w = f2bf(v.w);
    *reinterpret_cast<ushort4*>(hb + (size_t)row * KDIM + c4) = o;
  }
}

// ---------------------------------------------------------------------------
// Coarse histogram: cnt[src>>7]++ via per-block LDS hist, then merge.
// ---------------------------------------------------------------------------
__global__ __launch_bounds__(256) void chist(
    const int* __restrict__ src, int* __restrict__ cnt, int E, int NB) {
  __shared__ int lcnt[NB_MAX];
  for (int i = threadIdx.x; i < NB; i += 256) lcnt[i] = 0;
  __syncthreads();
  const int stride = gridDim.x * blockDim.x;
  for (int e = blockIdx.x * blockDim.x + threadIdx.x; e < E; e += stride)
    atomicAdd(&lcnt[src[e] >> 7], 1);
  __syncthreads();
  for (int i = threadIdx.x; i < NB; i += 256)
    if (lcnt[i]) atomicAdd(&cnt[i], lcnt[i]);
}

// ---------------------------------------------------------------------------
// Exclusive scan of cnt -> bstart[NB+1]; init gcursor = bstart. One wave.
// ---------------------------------------------------------------------------
__global__ void cscan(const int* __restrict__ cnt, int* __restrict__ bstart,
                      int* __restrict__ gcursor, int NB) {
  const int lane = threadIdx.x;   // 64 threads
  int carry = 0;
  for (int base = 0; base < NB; base += 64) {
    const int i = base + lane;
    const int c = (i < NB) ? cnt[i] : 0;
    int incl = c;
    for (int d = 1; d < 64; d <<= 1) {
      int t = __shfl_up(incl, d, 64);
      if (lane >= d) incl += t;
    }
    const int excl = carry + incl - c;
    if (i < NB) { bstart[i] = excl; gcursor[i] = excl; }
    carry += __shfl(incl, 63, 64);
  }
  if (lane == 0) bstart[NB] = carry;
}

// ---------------------------------------------------------------------------
// Partition edges into coarse buckets. Per-block LDS hist -> one global
// range-reservation atomic per (block,bucket) -> contiguous write runs.
// Record: x = dst | (src&127)<<17,  y = weight bits.
// ---------------------------------------------------------------------------
__global__ __launch_bounds__(256) void cpartition(
    const int* __restrict__ src, const int* __restrict__ dst,
    const float* __restrict__ ew,
    int* __restrict__ gcursor, int2* __restrict__ recs, int E, int NB) {
  __shared__ int pos[NB_MAX];
  const int c0 = blockIdx.x * PART_CHUNK;
  const int c1 = min(E, c0 + PART_CHUNK);
  for (int i = threadIdx.x; i < NB; i += 256) pos[i] = 0;
  __syncthreads();
  for (int i = c0 + threadIdx.x; i < c1; i += 256)
    atomicAdd(&pos[src[i] >> 7], 1);
  __syncthreads();
  for (int b = threadIdx.x; b < NB; b += 256) {
    const int c = pos[b];
    pos[b] = c ? atomicAdd(&gcursor[b], c) : 0;
  }
  __syncthreads();
  for (int i = c0 + threadIdx.x; i < c1; i += 256) {
    const int s = src[i];
    const int p = atomicAdd(&pos[s >> 7], 1);
    int2 r;
    r.x = dst[i] | ((s & 127) << 17);
    r.y = __float_as_int(ew[i]);
    recs[p] = r;
  }
}

// ---------------------------------------------------------------------------
// Aggregate: block = one 128-node coarse bucket, 8 waves. agg[128][128] f32
// in LDS; wave w exclusively owns node rows [16w,16w+16) -> no atomics.
// Each wave scans the bucket's records (broadcast load, wave-uniform skip);
// for owned records: gather 4B/lane from hb x-half (coalesced 256B/edge),
// float2 LDS read-modify-write (stride 8B -> 2-way, free). Then normalize
// and write neigh half as bf16, coalesced.
// ---------------------------------------------------------------------------
__global__ __launch_bounds__(512, 4) void cagg(
    unsigned short* __restrict__ hb,
    const int* __restrict__ bstart,
    const int2* __restrict__ recs, int N) {
  __shared__ float agg[CB_NODES][IN_DIM];
  __shared__ float wsum[CB_NODES];
  const int tid = threadIdx.x;
  const int lane = tid & 63;
  const int wv = tid >> 6;       // 0..7
  const int blk = blockIdx.x;

  for (int i = tid; i < CB_NODES * IN_DIM / 4; i += 512)
    *reinterpret_cast<float4*>(&agg[0][0] + (size_t)i * 4) = (float4){0.f, 0.f, 0.f, 0.f};
  if (tid < CB_NODES) wsum[tid] = 0.f;
  __syncthreads();

  const int e0 = bstart[blk];
  const int e1 = bstart[blk + 1];
  for (int i = e0; i < e1; ++i) {
    const int2 r = recs[i];               // wave-uniform broadcast load
    const int sl = r.x >> 17;             // local node 0..127
    if ((sl >> 4) != wv) continue;        // wave-uniform branch
    const int d = r.x & 0x1FFFF;
    const float w = __int_as_float(r.y);
    const unsigned v = *reinterpret_cast<const unsigned*>(hb + (size_t)d * KDIM + lane * 2);
    float2 cur = *reinterpret_cast<float2*>(&agg[sl][lane * 2]);
    cur.x += __uint_as_float((v & 0xffffu) << 16) * w;
    cur.y += __uint_as_float(v & 0xffff0000u) * w;
    *reinterpret_cast<float2*>(&agg[sl][lane * 2]) = cur;
    if (lane == 0) wsum[sl] += w;
  }
  __syncthreads();

#pragma unroll
  for (int r = 0; r < CB_NODES / 8; ++r) {   // 16 rows per wave
    const int row = wv * 16 + r;
    const int node = blk * CB_NODES + row;
    if (node < N) {
      const float m = fmaxf(wsum[row], EPS);
      const float a0 = agg[row][lane * 2] / m;
      const float a1 = agg[row][lane * 2 + 1] / m;
      *reinterpret_cast<unsigned*>(hb + (size_t)node * KDIM + IN_DIM + lane * 2) =
          pack2bf(a0, a1);
    }
  }
}

// ---------------------------------------------------------------------------
// MFMA GEMM: out = relu(hb @ W^T + b). Block = 256 rows x 256 cols, 8 waves.
// W staged f32->bf16 into LDS with XOR swizzle (byte ^= (j&7)<<4) so the
// 16-row-strided ds_read_b128 hits the 8-cycle floor instead of a 4-bank
// pileup. A-frags preloaded to registers; K-loop fully unrolled.
// ---------------------------------------------------------------------------
__global__ __launch_bounds__(512, 2) void sage_gemm_mfma(
    const unsigned short* __restrict__ hb,
    const float* __restrict__ W,
    const float* __restrict__ bias,
    float* __restrict__ out, int N) {
  __shared__ unsigned short Wl[OUT_DIM * KDIM];   // 128 KB, swizzled
  const int tid = threadIdx.x;
  const int lane = tid & 63;
  const int wv = tid >> 6;

  // stage W (f32, L2-hot) -> bf16 swizzled LDS. 8192 chunks of 8 elems.
  char* wl = reinterpret_cast<char*>(Wl);
  for (int ch = tid; ch < OUT_DIM * KDIM / 8; ch += 512) {
    const int elem = ch * 8;
    const int j = elem >> 8;          // W row 0..255
    const int col = elem & 255;       // multiple of 8
    const float4 w0 = *reinterpret_cast<const float4*>(W + elem);
    const float4 w1 = *reinterpret_cast<const float4*>(W + elem + 4);
    uint4 o;
    o.x = pack2bf(w0.x, w0.y); o.y = pack2bf(w0.z, w0.w);
    o.z = pack2bf(w1.x, w1.y); o.w = pack2bf(w1.z, w1.w);
    const int byte = (j << 9) | ((col * 2) ^ ((j & 7) << 4));
    *reinterpret_cast<uint4*>(wl + byte) = o;
  }

  // preload A fragments (overlaps with staging; vmcnt waited at first MFMA)
  const int row0 = blockIdx.x * 256 + wv * 32;
  const int kc = (lane >> 4) * 8;
  const unsigned short* arow0 = hb + (size_t)(row0 + (lane & 15)) * KDIM + kc;
  const unsigned short* arow1 = arow0 + 16 * KDIM;
  short8 a0[8], a1[8];
#pragma unroll
  for (int kk = 0; kk < 8; ++kk) {
    a0[kk] = *reinterpret_cast<const short8*>(arow0 + kk * 32);
    a1[kk] = *reinterpret_cast<const short8*>(arow1 + kk * 32);
  }

  __syncthreads();

  f32x4 acc[2][16];
#pragma unroll
  for (int i = 0; i < 2; ++i)
#pragma unroll
    for (int j = 0; j < 16; ++j) acc[i][j] = (f32x4){0.f, 0.f, 0.f, 0.f};

  const int jrow = lane & 15;
  const int kb0 = kc * 2;            // (lane>>4)*16
#pragma unroll
  for (int kk = 0; kk < 8; ++kk) {
    const int kbyte = kb0 + kk * 64;
#pragma unroll
    for (int ct = 0; ct < 16; ++ct) {
      const int j = ct * 16 + jrow;
      const short8 bf = *reinterpret_cast<const short8*>(
          wl + ((j << 9) | (kbyte ^ ((j & 7) << 4))));
      acc[0][ct] = __builtin_amdgcn_mfma_f32_16x16x32_bf16(a0[kk], bf, acc[0][ct], 0, 0, 0);
      acc[1][ct] = __builtin_amdgcn_mfma_f32_16x16x32_bf16(a1[kk], bf, acc[1][ct], 0, 0, 0);
    }
  }

  const int col = lane & 15;
  const int rquad = (lane >> 4) * 4;
#pragma unroll
  for (int ct = 0; ct < 16; ++ct) {
    const int j = ct * 16 + col;
    const float bj = bias[j];
#pragma unroll
    for (int rt = 0; rt < 2; ++rt) {
      const int rbase = row0 + rt * 16 + rquad;
      const f32x4 a = acc[rt][ct];
#pragma unroll
      for (int r = 0; r < 4; ++r) {
        const int row = rbase + r;
        if (row < N) out[(size_t)row * OUT_DIM + j] = fmaxf(a[r] + bj, 0.f);
      }
    }
  }
}

extern "C" void kernel_launch(void* const* d_in, const int* in_sizes, int n_in,
                              void* d_out, int out_size, void* d_ws, size_t ws_size,
                              hipStream_t stream) {
  const float* x  = (const float*)d_in[0];
  const int*   ei = (const int*)d_in[1];     // [2][E]
  const float* ew = (const float*)d_in[2];   // [E]
  const float* W  = (const float*)d_in[3];   // [OUT_DIM][KDIM]
  const float* b  = (const float*)d_in[4];   // [OUT_DIM]
  float* out = (float*)d_out;

  const int N = in_sizes[0] / IN_DIM;        // 100000
  const int E = in_sizes[2];                 // 1600000
  const int* src = ei;
  const int* dst = ei + E;

  const int gemm_blocks = (N + 255) / 256;   // 391
  const int Mpad = gemm_blocks * 256;        // 100096
  const int NB = (N + CB_NODES - 1) / CB_NODES;   // 782

  // ws layout (4-byte elems):
  //   hb[Mpad][256] bf16 | recs[E] int2 | cnt[NB_MAX] | bstart[NB_MAX+1] | gcursor[NB_MAX]
  unsigned short* hb = (unsigned short*)d_ws;
  int2* recs   = (int2*)(hb + (size_t)Mpad * KDIM);
  int* cnt     = (int*)(recs + E);
  int* bstart  = cnt + NB_MAX;
  int* gcursor = bstart + NB_MAX + 1;

  hipMemsetAsync(cnt, 0, NB * sizeof(int), stream);

  cvt_x<<<2048, 256, 0, stream>>>(x, hb, N);
  chist<<<256, 256, 0, stream>>>(src, cnt, E, NB);
  cscan<<<1, 64, 0, stream>>>(cnt, bstart, gcursor, NB);
  cpartition<<<(E + PART_CHUNK - 1) / PART_CHUNK, 256, 0, stream>>>(
      src, dst, ew, gcursor, recs, E, NB);
  cagg<<<NB, 512, 0, stream>>>(hb, bstart, recs, N);
  sage_gemm_mfma<<<gemm_blocks, 512, 0, stream>>>(hb, W, b, out, N);
}

// Round 6
// 401.230 us; speedup vs baseline: 1.9699x; 1.9699x over previous
//
#include <hip/hip_runtime.h>
#include <hip/hip_bf16.h>

#define IN_DIM 128
#define OUT_DIM 256
#define KDIM 256            // 2*IN_DIM
#define EPS 1e-12f
#define CB_NODES 128        // nodes per coarse bucket
#define NB_MAX 1024         // max coarse buckets (N<=131072)
#define PART_CHUNK 8192
#define CAP 2560            // records per LDS sort chunk (mean bucket ~2046, max ~2250)

typedef __attribute__((ext_vector_type(8))) short short8;   // 8 bf16
typedef __attribute__((ext_vector_type(4))) float f32x4;

static __device__ __forceinline__ unsigned short f2bf(float f) {
  __hip_bfloat16 h = __float2bfloat16(f);   // RNE
  return *reinterpret_cast<unsigned short*>(&h);
}
static __device__ __forceinline__ unsigned pack2bf(float a, float b) {
  return (unsigned)f2bf(a) | ((unsigned)f2bf(b) << 16);
}
static __device__ __forceinline__ float bf_lo(unsigned v) {
  return __uint_as_float((v & 0xffffu) << 16);
}
static __device__ __forceinline__ float bf_hi(unsigned v) {
  return __uint_as_float(v & 0xffff0000u);
}

// ---------------------------------------------------------------------------
// Convert x (f32 [N][128]) into cols 0..127 of hb (bf16 [Mpad][256]).
// ---------------------------------------------------------------------------
__global__ __launch_bounds__(256) void cvt_x(
    const float* __restrict__ x, unsigned short* __restrict__ hb, int N) {
  const int total = N * 32;                 // N*128/4
  const int stride = gridDim.x * blockDim.x;
  for (int idx = blockIdx.x * blockDim.x + threadIdx.x; idx < total; idx += stride) {
    const int row = idx >> 5;
    const int c4 = (idx & 31) * 4;
    const float4 v = *reinterpret_cast<const float4*>(x + (size_t)row * IN_DIM + c4);
    ushort4 o;
    o.x = f2bf(v.x); o.y = f2bf(v.y); o.z = f2bf(v.z); o.w = f2bf(v.w);
    *reinterpret_cast<ushort4*>(hb + (size_t)row * KDIM + c4) = o;
  }
}

// ---------------------------------------------------------------------------
// Coarse histogram: cnt[src>>7]++ via per-block LDS hist, then merge.
// ---------------------------------------------------------------------------
__global__ __launch_bounds__(256) void chist(
    const int* __restrict__ src, int* __restrict__ cnt, int E, int NB) {
  __shared__ int lcnt[NB_MAX];
  for (int i = threadIdx.x; i < NB; i += 256) lcnt[i] = 0;
  __syncthreads();
  const int stride = gridDim.x * blockDim.x;
  for (int e = blockIdx.x * blockDim.x + threadIdx.x; e < E; e += stride)
    atomicAdd(&lcnt[src[e] >> 7], 1);
  __syncthreads();
  for (int i = threadIdx.x; i < NB; i += 256)
    if (lcnt[i]) atomicAdd(&cnt[i], lcnt[i]);
}

// ---------------------------------------------------------------------------
// Exclusive scan of cnt -> bstart[NB+1]; init gcursor = bstart. One wave.
// ---------------------------------------------------------------------------
__global__ void cscan(const int* __restrict__ cnt, int* __restrict__ bstart,
                      int* __restrict__ gcursor, int NB) {
  const int lane = threadIdx.x;   // 64 threads
  int carry = 0;
  for (int base = 0; base < NB; base += 64) {
    const int i = base + lane;
    const int c = (i < NB) ? cnt[i] : 0;
    int incl = c;
    for (int d = 1; d < 64; d <<= 1) {
      int t = __shfl_up(incl, d, 64);
      if (lane >= d) incl += t;
    }
    const int excl = carry + incl - c;
    if (i < NB) { bstart[i] = excl; gcursor[i] = excl; }
    carry += __shfl(incl, 63, 64);
  }
  if (lane == 0) bstart[NB] = carry;
}

// ---------------------------------------------------------------------------
// Partition edges into coarse buckets. Per-block LDS hist -> one global
// range-reservation atomic per (block,bucket) -> contiguous write runs.
// Record: x = dst | (src&127)<<17,  y = weight bits.
// ---------------------------------------------------------------------------
__global__ __launch_bounds__(256) void cpartition(
    const int* __restrict__ src, const int* __restrict__ dst,
    const float* __restrict__ ew,
    int* __restrict__ gcursor, int2* __restrict__ recs, int E, int NB) {
  __shared__ int pos[NB_MAX];
  const int c0 = blockIdx.x * PART_CHUNK;
  const int c1 = min(E, c0 + PART_CHUNK);
  for (int i = threadIdx.x; i < NB; i += 256) pos[i] = 0;
  __syncthreads();
  for (int i = c0 + threadIdx.x; i < c1; i += 256)
    atomicAdd(&pos[src[i] >> 7], 1);
  __syncthreads();
  for (int b = threadIdx.x; b < NB; b += 256) {
    const int c = pos[b];
    pos[b] = c ? atomicAdd(&gcursor[b], c) : 0;
  }
  __syncthreads();
  for (int i = c0 + threadIdx.x; i < c1; i += 256) {
    const int s = src[i];
    const int p = atomicAdd(&pos[s >> 7], 1);
    int2 r;
    r.x = dst[i] | ((s & 127) << 17);
    r.y = __float_as_int(ew[i]);
    recs[p] = r;
  }
}

// ---------------------------------------------------------------------------
// Aggregate v2: block = one 128-node bucket, 8 waves.
// Chunk of <=CAP records: LDS counting sort by local node id (hist -> scan ->
// scatter), then wave w aggregates its 16 exclusively-owned nodes from the
// sorted contiguous record runs, 4-edge unroll (4 independent gathers in
// flight), f32 register accumulators (statically indexed). Normalize + write
// bf16 neigh once at the end.
// ---------------------------------------------------------------------------
__global__ __launch_bounds__(512) void cagg(
    unsigned short* __restrict__ hb,
    const int* __restrict__ bstart,
    const int2* __restrict__ recs, int N) {
  __shared__ int2 lrec[CAP];                 // 20 KB
  __shared__ int lstart[CB_NODES + 1];
  __shared__ int lcur[CB_NODES];             // doubles as hist
  const int tid = threadIdx.x;
  const int lane = tid & 63;
  const int wv = tid >> 6;                   // 0..7
  const int blk = blockIdx.x;
  const int e0 = bstart[blk];
  const int e1 = bstart[blk + 1];

  float ax[16], ay[16], ws[16];
#pragma unroll
  for (int n = 0; n < 16; ++n) { ax[n] = 0.f; ay[n] = 0.f; ws[n] = 0.f; }

  for (int base = e0; base < e1; base += CAP) {
    const int m = min(CAP, e1 - base);
    if (tid < CB_NODES) lcur[tid] = 0;
    __syncthreads();
    // pass 1: histogram by local node
    for (int i = tid; i < m; i += 512)
      atomicAdd(&lcur[recs[base + i].x >> 17], 1);
    __syncthreads();
    // scan (wave 0): 128 entries in 2 rounds of 64
    if (wv == 0) {
      int carry = 0;
#pragma unroll
      for (int rr = 0; rr < 2; ++rr) {
        const int idx = rr * 64 + lane;
        const int c = lcur[idx];
        int incl = c;
#pragma unroll
        for (int d = 1; d < 64; d <<= 1) {
          int t = __shfl_up(incl, d, 64);
          if (lane >= d) incl += t;
        }
        lstart[idx] = carry + incl - c;
        carry += __shfl(incl, 63, 64);
      }
      if (lane == 0) lstart[CB_NODES] = carry;
    }
    __syncthreads();
    if (tid < CB_NODES) lcur[tid] = lstart[tid];
    __syncthreads();
    // pass 2: scatter into sorted LDS order (records re-read, L2-hot)
    for (int i = tid; i < m; i += 512) {
      const int2 r = recs[base + i];
      const int p = atomicAdd(&lcur[r.x >> 17], 1);
      lrec[p] = r;
    }
    __syncthreads();
    // aggregate: wave wv owns nodes [wv*16, wv*16+16)
#pragma unroll
    for (int n = 0; n < 16; ++n) {
      const int rs = lstart[wv * 16 + n];
      const int re = lstart[wv * 16 + n + 1];
      int j = rs;
      for (; j + 4 <= re; j += 4) {
        const int2 r0 = lrec[j + 0];
        const int2 r1 = lrec[j + 1];
        const int2 r2 = lrec[j + 2];
        const int2 r3 = lrec[j + 3];
        const unsigned v0 = *reinterpret_cast<const unsigned*>(
            hb + (size_t)(r0.x & 0x1FFFF) * KDIM + lane * 2);
        const unsigned v1 = *reinterpret_cast<const unsigned*>(
            hb + (size_t)(r1.x & 0x1FFFF) * KDIM + lane * 2);
        const unsigned v2 = *reinterpret_cast<const unsigned*>(
            hb + (size_t)(r2.x & 0x1FFFF) * KDIM + lane * 2);
        const unsigned v3 = *reinterpret_cast<const unsigned*>(
            hb + (size_t)(r3.x & 0x1FFFF) * KDIM + lane * 2);
        const float w0 = __int_as_float(r0.y);
        const float w1 = __int_as_float(r1.y);
        const float w2 = __int_as_float(r2.y);
        const float w3 = __int_as_float(r3.y);
        ax[n] += bf_lo(v0) * w0 + bf_lo(v1) * w1 + bf_lo(v2) * w2 + bf_lo(v3) * w3;
        ay[n] += bf_hi(v0) * w0 + bf_hi(v1) * w1 + bf_hi(v2) * w2 + bf_hi(v3) * w3;
        ws[n] += w0 + w1 + w2 + w3;
      }
      for (; j < re; ++j) {
        const int2 r = lrec[j];
        const unsigned v = *reinterpret_cast<const unsigned*>(
            hb + (size_t)(r.x & 0x1FFFF) * KDIM + lane * 2);
        const float w = __int_as_float(r.y);
        ax[n] += bf_lo(v) * w;
        ay[n] += bf_hi(v) * w;
        ws[n] += w;
      }
    }
    __syncthreads();   // protect lrec/lcur before next chunk
  }

#pragma unroll
  for (int n = 0; n < 16; ++n) {
    const int row = wv * 16 + n;
    const int node = blk * CB_NODES + row;
    if (node < N) {
      const float mm = fmaxf(ws[n], EPS);
      *reinterpret_cast<unsigned*>(hb + (size_t)node * KDIM + IN_DIM + lane * 2) =
          pack2bf(ax[n] / mm, ay[n] / mm);
    }
  }
}

// ---------------------------------------------------------------------------
// MFMA GEMM: out = relu(hb @ W^T + b). Block = 256 rows x 256 cols, 8 waves.
// W staged f32->bf16 into LDS with XOR swizzle; A-frags preloaded; unchanged
// from round 4 (counters pending — cagg monopolized top-5).
// ---------------------------------------------------------------------------
__global__ __launch_bounds__(512, 2) void sage_gemm_mfma(
    const unsigned short* __restrict__ hb,
    const float* __restrict__ W,
    const float* __restrict__ bias,
    float* __restrict__ out, int N) {
  __shared__ unsigned short Wl[OUT_DIM * KDIM];   // 128 KB, swizzled
  const int tid = threadIdx.x;
  const int lane = tid & 63;
  const int wv = tid >> 6;

  char* wl = reinterpret_cast<char*>(Wl);
  for (int ch = tid; ch < OUT_DIM * KDIM / 8; ch += 512) {
    const int elem = ch * 8;
    const int j = elem >> 8;          // W row 0..255
    const int col = elem & 255;       // multiple of 8
    const float4 w0 = *reinterpret_cast<const float4*>(W + elem);
    const float4 w1 = *reinterpret_cast<const float4*>(W + elem + 4);
    uint4 o;
    o.x = pack2bf(w0.x, w0.y); o.y = pack2bf(w0.z, w0.w);
    o.z = pack2bf(w1.x, w1.y); o.w = pack2bf(w1.z, w1.w);
    const int byte = (j << 9) | ((col * 2) ^ ((j & 7) << 4));
    *reinterpret_cast<uint4*>(wl + byte) = o;
  }

  const int row0 = blockIdx.x * 256 + wv * 32;
  const int kc = (lane >> 4) * 8;
  const unsigned short* arow0 = hb + (size_t)(row0 + (lane & 15)) * KDIM + kc;
  const unsigned short* arow1 = arow0 + 16 * KDIM;
  short8 a0[8], a1[8];
#pragma unroll
  for (int kk = 0; kk < 8; ++kk) {
    a0[kk] = *reinterpret_cast<const short8*>(arow0 + kk * 32);
    a1[kk] = *reinterpret_cast<const short8*>(arow1 + kk * 32);
  }

  __syncthreads();

  f32x4 acc[2][16];
#pragma unroll
  for (int i = 0; i < 2; ++i)
#pragma unroll
    for (int j = 0; j < 16; ++j) acc[i][j] = (f32x4){0.f, 0.f, 0.f, 0.f};

  const int jrow = lane & 15;
  const int kb0 = kc * 2;            // (lane>>4)*16
#pragma unroll
  for (int kk = 0; kk < 8; ++kk) {
    const int kbyte = kb0 + kk * 64;
#pragma unroll
    for (int ct = 0; ct < 16; ++ct) {
      const int j = ct * 16 + jrow;
      const short8 bf = *reinterpret_cast<const short8*>(
          wl + ((j << 9) | (kbyte ^ ((j & 7) << 4))));
      acc[0][ct] = __builtin_amdgcn_mfma_f32_16x16x32_bf16(a0[kk], bf, acc[0][ct], 0, 0, 0);
      acc[1][ct] = __builtin_amdgcn_mfma_f32_16x16x32_bf16(a1[kk], bf, acc[1][ct], 0, 0, 0);
    }
  }

  const int col = lane & 15;
  const int rquad = (lane >> 4) * 4;
#pragma unroll
  for (int ct = 0; ct < 16; ++ct) {
    const int j = ct * 16 + col;
    const float bj = bias[j];
#pragma unroll
    for (int rt = 0; rt < 2; ++rt) {
      const int rbase = row0 + rt * 16 + rquad;
      const f32x4 a = acc[rt][ct];
#pragma unroll
      for (int r = 0; r < 4; ++r) {
        const int row = rbase + r;
        if (row < N) out[(size_t)row * OUT_DIM + j] = fmaxf(a[r] + bj, 0.f);
      }
    }
  }
}

extern "C" void kernel_launch(void* const* d_in, const int* in_sizes, int n_in,
                              void* d_out, int out_size, void* d_ws, size_t ws_size,
                              hipStream_t stream) {
  const float* x  = (const float*)d_in[0];
  const int*   ei = (const int*)d_in[1];     // [2][E]
  const float* ew = (const float*)d_in[2];   // [E]
  const float* W  = (const float*)d_in[3];   // [OUT_DIM][KDIM]
  const float* b  = (const float*)d_in[4];   // [OUT_DIM]
  float* out = (float*)d_out;

  const int N = in_sizes[0] / IN_DIM;        // 100000
  const int E = in_sizes[2];                 // 1600000
  const int* src = ei;
  const int* dst = ei + E;

  const int gemm_blocks = (N + 255) / 256;   // 391
  const int Mpad = gemm_blocks * 256;        // 100096
  const int NB = (N + CB_NODES - 1) / CB_NODES;   // 782

  // ws layout (4-byte elems):
  //   hb[Mpad][256] bf16 | recs[E] int2 | cnt[NB_MAX] | bstart[NB_MAX+1] | gcursor[NB_MAX]
  unsigned short* hb = (unsigned short*)d_ws;
  int2* recs   = (int2*)(hb + (size_t)Mpad * KDIM);
  int* cnt     = (int*)(recs + E);
  int* bstart  = cnt + NB_MAX;
  int* gcursor = bstart + NB_MAX + 1;

  hipMemsetAsync(cnt, 0, NB * sizeof(int), stream);

  cvt_x<<<2048, 256, 0, stream>>>(x, hb, N);
  chist<<<256, 256, 0, stream>>>(src, cnt, E, NB);
  cscan<<<1, 64, 0, stream>>>(cnt, bstart, gcursor, NB);
  cpartition<<<(E + PART_CHUNK - 1) / PART_CHUNK, 256, 0, stream>>>(
      src, dst, ew, gcursor, recs, E, NB);
  cagg<<<NB, 512, 0, stream>>>(hb, bstart, recs, N);
  sage_gemm_mfma<<<gemm_blocks, 512, 0, stream>>>(hb, W, b, out, N);
}

// Round 7
// 380.580 us; speedup vs baseline: 2.0768x; 1.0543x over previous
//
#include <hip/hip_runtime.h>
#include <hip/hip_bf16.h>

#define IN_DIM 128
#define OUT_DIM 256
#define KDIM 256            // 2*IN_DIM
#define EPS 1e-12f
#define CB_NODES 128        // nodes per coarse bucket
#define NB_MAX 1024         // max coarse buckets (N<=131072)
#define PART_CHUNK 2048     // 782 partition blocks -> 3/CU all-resident
#define CAP 2560            // records per LDS sort chunk (mean bucket ~2046, max ~2270)

typedef __attribute__((ext_vector_type(8))) short short8;   // 8 bf16
typedef __attribute__((ext_vector_type(4))) float f32x4;

static __device__ __forceinline__ unsigned short f2bf(float f) {
  __hip_bfloat16 h = __float2bfloat16(f);   // RNE
  return *reinterpret_cast<unsigned short*>(&h);
}
static __device__ __forceinline__ unsigned pack2bf(float a, float b) {
  return (unsigned)f2bf(a) | ((unsigned)f2bf(b) << 16);
}
static __device__ __forceinline__ float bf_lo(unsigned v) {
  return __uint_as_float((v & 0xffffu) << 16);
}
static __device__ __forceinline__ float bf_hi(unsigned v) {
  return __uint_as_float(v & 0xffff0000u);
}

// ---------------------------------------------------------------------------
// Convert x (f32 [N][128]) into cols 0..127 of hb (bf16 [Mpad][256]).
// ---------------------------------------------------------------------------
__global__ __launch_bounds__(256) void cvt_x(
    const float* __restrict__ x, unsigned short* __restrict__ hb, int N) {
  const int total = N * 32;                 // N*128/4
  const int stride = gridDim.x * blockDim.x;
  for (int idx = blockIdx.x * blockDim.x + threadIdx.x; idx < total; idx += stride) {
    const int row = idx >> 5;
    const int c4 = (idx & 31) * 4;
    const float4 v = *reinterpret_cast<const float4*>(x + (size_t)row * IN_DIM + c4);
    ushort4 o;
    o.x = f2bf(v.x); o.y = f2bf(v.y); o.z = f2bf(v.z); o.w = f2bf(v.w);
    *reinterpret_cast<ushort4*>(hb + (size_t)row * KDIM + c4) = o;
  }
}

// ---------------------------------------------------------------------------
// Convert W (f32 [256][256]) -> Wb (bf16, same layout). One-shot, 64 blocks.
// ---------------------------------------------------------------------------
__global__ __launch_bounds__(256) void cvt_w(
    const float* __restrict__ W, unsigned short* __restrict__ Wb) {
  const int base = (blockIdx.x * blockDim.x + threadIdx.x) * 4;
  const float4 v = *reinterpret_cast<const float4*>(W + base);
  ushort4 o;
  o.x = f2bf(v.x); o.y = f2bf(v.y); o.z = f2bf(v.z); o.w = f2bf(v.w);
  *reinterpret_cast<ushort4*>(Wb + base) = o;
}

// ---------------------------------------------------------------------------
// Coarse histogram: cnt[src>>7]++ via per-block LDS hist, then merge.
// ---------------------------------------------------------------------------
__global__ __launch_bounds__(256) void chist(
    const int* __restrict__ src, int* __restrict__ cnt, int E, int NB) {
  __shared__ int lcnt[NB_MAX];
  for (int i = threadIdx.x; i < NB; i += 256) lcnt[i] = 0;
  __syncthreads();
  const int stride = gridDim.x * blockDim.x;
  for (int e = blockIdx.x * blockDim.x + threadIdx.x; e < E; e += stride)
    atomicAdd(&lcnt[src[e] >> 7], 1);
  __syncthreads();
  for (int i = threadIdx.x; i < NB; i += 256)
    if (lcnt[i]) atomicAdd(&cnt[i], lcnt[i]);
}

// ---------------------------------------------------------------------------
// Exclusive scan of cnt -> bstart[NB+1]; init gcursor = bstart. One wave.
// ---------------------------------------------------------------------------
__global__ void cscan(const int* __restrict__ cnt, int* __restrict__ bstart,
                      int* __restrict__ gcursor, int NB) {
  const int lane = threadIdx.x;   // 64 threads
  int carry = 0;
  for (int base = 0; base < NB; base += 64) {
    const int i = base + lane;
    const int c = (i < NB) ? cnt[i] : 0;
    int incl = c;
    for (int d = 1; d < 64; d <<= 1) {
      int t = __shfl_up(incl, d, 64);
      if (lane >= d) incl += t;
    }
    const int excl = carry + incl - c;
    if (i < NB) { bstart[i] = excl; gcursor[i] = excl; }
    carry += __shfl(incl, 63, 64);
  }
  if (lane == 0) bstart[NB] = carry;
}

// ---------------------------------------------------------------------------
// Partition edges into coarse buckets. Per-block LDS hist -> one global
// range-reservation atomic per (block,bucket) -> contiguous write runs.
// Record: x = dst | (src&127)<<17,  y = weight bits.
// ---------------------------------------------------------------------------
__global__ __launch_bounds__(256) void cpartition(
    const int* __restrict__ src, const int* __restrict__ dst,
    const float* __restrict__ ew,
    int* __restrict__ gcursor, int2* __restrict__ recs, int E, int NB) {
  __shared__ int pos[NB_MAX];
  const int c0 = blockIdx.x * PART_CHUNK;
  const int c1 = min(E, c0 + PART_CHUNK);
  for (int i = threadIdx.x; i < NB; i += 256) pos[i] = 0;
  __syncthreads();
  for (int i = c0 + threadIdx.x; i < c1; i += 256)
    atomicAdd(&pos[src[i] >> 7], 1);
  __syncthreads();
  for (int b = threadIdx.x; b < NB; b += 256) {
    const int c = pos[b];
    pos[b] = c ? atomicAdd(&gcursor[b], c) : 0;
  }
  __syncthreads();
  for (int i = c0 + threadIdx.x; i < c1; i += 256) {
    const int s = src[i];
    const int p = atomicAdd(&pos[s >> 7], 1);
    int2 r;
    r.x = dst[i] | ((s & 127) << 17);
    r.y = __float_as_int(ew[i]);
    recs[p] = r;
  }
}

// ---------------------------------------------------------------------------
// Aggregate fast path: bucket fits in one CAP chunk (always, for this input).
// LDS counting sort, then wave wv aggregates its 16 owned nodes from sorted
// contiguous runs with per-node LOCAL accumulators (3 live VGPRs) and
// 8-deep gather unroll. launch_bounds(512,8) pins VGPR<=64 so all 782
// blocks stay co-resident at 8 waves/SIMD.
// ---------------------------------------------------------------------------
__global__ __launch_bounds__(512, 8) void cagg_fast(
    unsigned short* __restrict__ hb,
    const int* __restrict__ bstart,
    const int2* __restrict__ recs, int N) {
  __shared__ int2 lrec[CAP];                 // 20 KB
  __shared__ int lstart[CB_NODES + 1];
  __shared__ int lcur[CB_NODES];
  const int tid = threadIdx.x;
  const int lane = tid & 63;
  const int wv = tid >> 6;                   // 0..7
  const int blk = blockIdx.x;
  const int e0 = bstart[blk];
  const int e1 = bstart[blk + 1];
  const int m = e1 - e0;
  if (m > CAP) return;                       // rare: handled by cagg_slow

  if (tid < CB_NODES) lcur[tid] = 0;
  __syncthreads();
  for (int i = tid; i < m; i += 512)
    atomicAdd(&lcur[recs[e0 + i].x >> 17], 1);
  __syncthreads();
  if (wv == 0) {
    int carry = 0;
#pragma unroll
    for (int rr = 0; rr < 2; ++rr) {
      const int idx = rr * 64 + lane;
      const int c = lcur[idx];
      int incl = c;
#pragma unroll
      for (int d = 1; d < 64; d <<= 1) {
        int t = __shfl_up(incl, d, 64);
        if (lane >= d) incl += t;
      }
      lstart[idx] = carry + incl - c;
      carry += __shfl(incl, 63, 64);
    }
    if (lane == 0) lstart[CB_NODES] = carry;
  }
  __syncthreads();
  if (tid < CB_NODES) lcur[tid] = lstart[tid];
  __syncthreads();
  for (int i = tid; i < m; i += 512) {
    const int2 r = recs[e0 + i];
    lrec[atomicAdd(&lcur[r.x >> 17], 1)] = r;
  }
  __syncthreads();

  for (int n = 0; n < 16; ++n) {
    const int rs = lstart[wv * 16 + n];
    const int re = lstart[wv * 16 + n + 1];
    float ax = 0.f, ay = 0.f, ws = 0.f;
    int j = rs;
    for (; j + 8 <= re; j += 8) {
      const int2 r0 = lrec[j + 0];
      const int2 r1 = lrec[j + 1];
      const int2 r2 = lrec[j + 2];
      const int2 r3 = lrec[j + 3];
      const int2 r4 = lrec[j + 4];
      const int2 r5 = lrec[j + 5];
      const int2 r6 = lrec[j + 6];
      const int2 r7 = lrec[j + 7];
      const unsigned v0 = *reinterpret_cast<const unsigned*>(hb + (size_t)(r0.x & 0x1FFFF) * KDIM + lane * 2);
      const unsigned v1 = *reinterpret_cast<const unsigned*>(hb + (size_t)(r1.x & 0x1FFFF) * KDIM + lane * 2);
      const unsigned v2 = *reinterpret_cast<const unsigned*>(hb + (size_t)(r2.x & 0x1FFFF) * KDIM + lane * 2);
      const unsigned v3 = *reinterpret_cast<const unsigned*>(hb + (size_t)(r3.x & 0x1FFFF) * KDIM + lane * 2);
      const unsigned v4 = *reinterpret_cast<const unsigned*>(hb + (size_t)(r4.x & 0x1FFFF) * KDIM + lane * 2);
      const unsigned v5 = *reinterpret_cast<const unsigned*>(hb + (size_t)(r5.x & 0x1FFFF) * KDIM + lane * 2);
      const unsigned v6 = *reinterpret_cast<const unsigned*>(hb + (size_t)(r6.x & 0x1FFFF) * KDIM + lane * 2);
      const unsigned v7 = *reinterpret_cast<const unsigned*>(hb + (size_t)(r7.x & 0x1FFFF) * KDIM + lane * 2);
      const float w0 = __int_as_float(r0.y), w1 = __int_as_float(r1.y);
      const float w2 = __int_as_float(r2.y), w3 = __int_as_float(r3.y);
      const float w4 = __int_as_float(r4.y), w5 = __int_as_float(r5.y);
      const float w6 = __int_as_float(r6.y), w7 = __int_as_float(r7.y);
      ax += bf_lo(v0) * w0 + bf_lo(v1) * w1 + bf_lo(v2) * w2 + bf_lo(v3) * w3
          + bf_lo(v4) * w4 + bf_lo(v5) * w5 + bf_lo(v6) * w6 + bf_lo(v7) * w7;
      ay += bf_hi(v0) * w0 + bf_hi(v1) * w1 + bf_hi(v2) * w2 + bf_hi(v3) * w3
          + bf_hi(v4) * w4 + bf_hi(v5) * w5 + bf_hi(v6) * w6 + bf_hi(v7) * w7;
      ws += w0 + w1 + w2 + w3 + w4 + w5 + w6 + w7;
    }
    for (; j + 2 <= re; j += 2) {
      const int2 r0 = lrec[j + 0];
      const int2 r1 = lrec[j + 1];
      const unsigned v0 = *reinterpret_cast<const unsigned*>(hb + (size_t)(r0.x & 0x1FFFF) * KDIM + lane * 2);
      const unsigned v1 = *reinterpret_cast<const unsigned*>(hb + (size_t)(r1.x & 0x1FFFF) * KDIM + lane * 2);
      const float w0 = __int_as_float(r0.y), w1 = __int_as_float(r1.y);
      ax += bf_lo(v0) * w0 + bf_lo(v1) * w1;
      ay += bf_hi(v0) * w0 + bf_hi(v1) * w1;
      ws += w0 + w1;
    }
    if (j < re) {
      const int2 r = lrec[j];
      const unsigned v = *reinterpret_cast<const unsigned*>(hb + (size_t)(r.x & 0x1FFFF) * KDIM + lane * 2);
      const float w = __int_as_float(r.y);
      ax += bf_lo(v) * w;
      ay += bf_hi(v) * w;
      ws += w;
    }
    const int node = blk * CB_NODES + wv * 16 + n;
    if (node < N) {
      const float mm = fmaxf(ws, EPS);
      *reinterpret_cast<unsigned*>(hb + (size_t)node * KDIM + IN_DIM + lane * 2) =
          pack2bf(ax / mm, ay / mm);
    }
  }
}

// ---------------------------------------------------------------------------
// Aggregate slow path (correctness fallback for buckets > CAP; no-op sweep
// for this input). Round-6 multi-chunk version with persistent reg arrays.
// ---------------------------------------------------------------------------
__global__ __launch_bounds__(512) void cagg_slow(
    unsigned short* __restrict__ hb,
    const int* __restrict__ bstart,
    const int2* __restrict__ recs, int N) {
  const int blk = blockIdx.x;
  const int e0 = bstart[blk];
  const int e1 = bstart[blk + 1];
  if (e1 - e0 <= CAP) return;                // handled by cagg_fast

  __shared__ int2 lrec[CAP];
  __shared__ int lstart[CB_NODES + 1];
  __shared__ int lcur[CB_NODES];
  const int tid = threadIdx.x;
  const int lane = tid & 63;
  const int wv = tid >> 6;

  float ax[16], ay[16], ws[16];
#pragma unroll
  for (int n = 0; n < 16; ++n) { ax[n] = 0.f; ay[n] = 0.f; ws[n] = 0.f; }

  for (int base = e0; base < e1; base += CAP) {
    const int m = min(CAP, e1 - base);
    if (tid < CB_NODES) lcur[tid] = 0;
    __syncthreads();
    for (int i = tid; i < m; i += 512)
      atomicAdd(&lcur[recs[base + i].x >> 17], 1);
    __syncthreads();
    if (wv == 0) {
      int carry = 0;
#pragma unroll
      for (int rr = 0; rr < 2; ++rr) {
        const int idx = rr * 64 + lane;
        const int c = lcur[idx];
        int incl = c;
#pragma unroll
        for (int d = 1; d < 64; d <<= 1) {
          int t = __shfl_up(incl, d, 64);
          if (lane >= d) incl += t;
        }
        lstart[idx] = carry + incl - c;
        carry += __shfl(incl, 63, 64);
      }
      if (lane == 0) lstart[CB_NODES] = carry;
    }
    __syncthreads();
    if (tid < CB_NODES) lcur[tid] = lstart[tid];
    __syncthreads();
    for (int i = tid; i < m; i += 512) {
      const int2 r = recs[base + i];
      lrec[atomicAdd(&lcur[r.x >> 17], 1)] = r;
    }
    __syncthreads();
#pragma unroll
    for (int n = 0; n < 16; ++n) {
      const int rs = lstart[wv * 16 + n];
      const int re = lstart[wv * 16 + n + 1];
      for (int j = rs; j < re; ++j) {
        const int2 r = lrec[j];
        const unsigned v = *reinterpret_cast<const unsigned*>(
            hb + (size_t)(r.x & 0x1FFFF) * KDIM + lane * 2);
        const float w = __int_as_float(r.y);
        ax[n] += bf_lo(v) * w;
        ay[n] += bf_hi(v) * w;
        ws[n] += w;
      }
    }
    __syncthreads();
  }

#pragma unroll
  for (int n = 0; n < 16; ++n) {
    const int node = blk * CB_NODES + wv * 16 + n;
    if (node < N) {
      const float mm = fmaxf(ws[n], EPS);
      *reinterpret_cast<unsigned*>(hb + (size_t)node * KDIM + IN_DIM + lane * 2) =
          pack2bf(ax[n] / mm, ay[n] / mm);
    }
  }
}

// ---------------------------------------------------------------------------
// MFMA GEMM: out = relu(hb @ Wb^T + b). Block = 256 rows x 256 cols, 8 waves.
// Wb (bf16) staged into LDS with XOR swizzle; A-frags preloaded to regs.
// ---------------------------------------------------------------------------
__global__ __launch_bounds__(512, 2) void sage_gemm_mfma(
    const unsigned short* __restrict__ hb,
    const unsigned short* __restrict__ Wb,
    const float* __restrict__ bias,
    float* __restrict__ out, int N) {
  __shared__ unsigned short Wl[OUT_DIM * KDIM];   // 128 KB, swizzled
  const int tid = threadIdx.x;
  const int lane = tid & 63;
  const int wv = tid >> 6;

  char* wl = reinterpret_cast<char*>(Wl);
  const uint4* wbv = reinterpret_cast<const uint4*>(Wb);
  for (int ch = tid; ch < OUT_DIM * KDIM / 8; ch += 512) {
    const int elem = ch * 8;
    const int j = elem >> 8;          // W row 0..255
    const int col = elem & 255;       // multiple of 8
    const uint4 o = wbv[ch];
    const int byte = (j << 9) | ((col * 2) ^ ((j & 7) << 4));
    *reinterpret_cast<uint4*>(wl + byte) = o;
  }

  const int row0 = blockIdx.x * 256 + wv * 32;
  const int kc = (lane >> 4) * 8;
  const unsigned short* arow0 = hb + (size_t)(row0 + (lane & 15)) * KDIM + kc;
  const unsigned short* arow1 = arow0 + 16 * KDIM;
  short8 a0[8], a1[8];
#pragma unroll
  for (int kk = 0; kk < 8; ++kk) {
    a0[kk] = *reinterpret_cast<const short8*>(arow0 + kk * 32);
    a1[kk] = *reinterpret_cast<const short8*>(arow1 + kk * 32);
  }

  __syncthreads();

  f32x4 acc[2][16];
#pragma unroll
  for (int i = 0; i < 2; ++i)
#pragma unroll
    for (int j = 0; j < 16; ++j) acc[i][j] = (f32x4){0.f, 0.f, 0.f, 0.f};

  const int jrow = lane & 15;
  const int kb0 = kc * 2;            // (lane>>4)*16
#pragma unroll
  for (int kk = 0; kk < 8; ++kk) {
    const int kbyte = kb0 + kk * 64;
#pragma unroll
    for (int ct = 0; ct < 16; ++ct) {
      const int j = ct * 16 + jrow;
      const short8 bf = *reinterpret_cast<const short8*>(
          wl + ((j << 9) | (kbyte ^ ((j & 7) << 4))));
      acc[0][ct] = __builtin_amdgcn_mfma_f32_16x16x32_bf16(a0[kk], bf, acc[0][ct], 0, 0, 0);
      acc[1][ct] = __builtin_amdgcn_mfma_f32_16x16x32_bf16(a1[kk], bf, acc[1][ct], 0, 0, 0);
    }
  }

  const int col = lane & 15;
  const int rquad = (lane >> 4) * 4;
#pragma unroll
  for (int ct = 0; ct < 16; ++ct) {
    const int j = ct * 16 + col;
    const float bj = bias[j];
#pragma unroll
    for (int rt = 0; rt < 2; ++rt) {
      const int rbase = row0 + rt * 16 + rquad;
      const f32x4 a = acc[rt][ct];
#pragma unroll
      for (int r = 0; r < 4; ++r) {
        const int row = rbase + r;
        if (row < N) out[(size_t)row * OUT_DIM + j] = fmaxf(a[r] + bj, 0.f);
      }
    }
  }
}

extern "C" void kernel_launch(void* const* d_in, const int* in_sizes, int n_in,
                              void* d_out, int out_size, void* d_ws, size_t ws_size,
                              hipStream_t stream) {
  const float* x  = (const float*)d_in[0];
  const int*   ei = (const int*)d_in[1];     // [2][E]
  const float* ew = (const float*)d_in[2];   // [E]
  const float* W  = (const float*)d_in[3];   // [OUT_DIM][KDIM]
  const float* b  = (const float*)d_in[4];   // [OUT_DIM]
  float* out = (float*)d_out;

  const int N = in_sizes[0] / IN_DIM;        // 100000
  const int E = in_sizes[2];                 // 1600000
  const int* src = ei;
  const int* dst = ei + E;

  const int gemm_blocks = (N + 255) / 256;   // 391
  const int Mpad = gemm_blocks * 256;        // 100096
  const int NB = (N + CB_NODES - 1) / CB_NODES;   // 782

  // ws layout (4-byte elems):
  //   hb[Mpad][256] bf16 | Wb[256][256] bf16 | recs[E] int2 |
  //   cnt[NB_MAX] | bstart[NB_MAX+1] | gcursor[NB_MAX]
  unsigned short* hb = (unsigned short*)d_ws;
  unsigned short* Wb = hb + (size_t)Mpad * KDIM;
  int2* recs   = (int2*)(Wb + OUT_DIM * KDIM);
  int* cnt     = (int*)(recs + E);
  int* bstart  = cnt + NB_MAX;
  int* gcursor = bstart + NB_MAX + 1;

  hipMemsetAsync(cnt, 0, NB * sizeof(int), stream);

  cvt_x<<<2048, 256, 0, stream>>>(x, hb, N);
  cvt_w<<<OUT_DIM * KDIM / 4 / 256, 256, 0, stream>>>(W, Wb);
  chist<<<512, 256, 0, stream>>>(src, cnt, E, NB);
  cscan<<<1, 64, 0, stream>>>(cnt, bstart, gcursor, NB);
  cpartition<<<(E + PART_CHUNK - 1) / PART_CHUNK, 256, 0, stream>>>(
      src, dst, ew, gcursor, recs, E, NB);
  cagg_fast<<<NB, 512, 0, stream>>>(hb, bstart, recs, N);
  cagg_slow<<<NB, 512, 0, stream>>>(hb, bstart, recs, N);
  sage_gemm_mfma<<<gemm_blocks, 512, 0, stream>>>(hb, Wb, b, out, N);
}